// Round 1
// 573.084 us; speedup vs baseline: 1.0529x; 1.0529x over previous
//
#include <hip/hip_runtime.h>

typedef short bf16x8 __attribute__((ext_vector_type(8)));
typedef float f32x4 __attribute__((ext_vector_type(4)));

#define QKV_FRAG_SH 110592
#define PROJ_FRAG_SH 36864
#define BIAS2_OFF_B 294912
#define SCALE 0.17677669529663689f
#define LOG2E 1.44269504088896341f
#define QSCALE (SCALE * LOG2E)
#define SMEM_BYTES 161792

__device__ __forceinline__ short f2bf(float f) {
  unsigned x = __float_as_uint(f);
  x = (x + 0x7FFFu + ((x >> 16) & 1u)) >> 16;
  return (short)x;
}

// Pre-transform: weights -> MFMA-fragment-contiguous bf16 layout.
// q rows pre-scaled by SCALE*log2(e); bias -> bias*log2(e) (QK acc-init, exp2 softmax).
__global__ void cvt_w(const float* __restrict__ qkv_w,
                      const float* __restrict__ proj_w,
                      const float* __restrict__ bias,
                      short* __restrict__ wfrag,
                      float* __restrict__ bias2) {
  int idx = blockIdx.x * 256 + threadIdx.x;
  if (idx < QKV_FRAG_SH) {
    int j = idx & 7, lane = (idx >> 3) & 63, t = idx >> 9;
    int nt = t / 6, ks = t - nt * 6;
    int n0 = nt * 16 + (lane & 15);
    float v = qkv_w[n0 * 192 + ks * 32 + (lane >> 4) * 8 + j];
    if (n0 < 192) v *= QSCALE;
    wfrag[idx] = f2bf(v);
  } else if (idx < QKV_FRAG_SH + PROJ_FRAG_SH) {
    int i2 = idx - QKV_FRAG_SH;
    int j = i2 & 7, lane = (i2 >> 3) & 63, t = i2 >> 9;
    int nt = t / 6, ks = t - nt * 6;
    wfrag[idx] = f2bf(proj_w[(nt * 16 + (lane & 15)) * 192 + ks * 32 + (lane >> 4) * 8 + j]);
  } else {
    int i3 = idx - (QKV_FRAG_SH + PROJ_FRAG_SH);
    bias2[i3] = bias[i3] * LOG2E;
  }
}

// Persistent: grid=256 blocks (1/CU), 768 threads (12 waves, 3/SIMD), 16 windows each.
// Per window: [prefetch next x] QKV | B1 | [write prefetch] attention (24 tasks, 2/wave) | B2 | proj.
__global__ __launch_bounds__(768, 3) void swin_fused(
    const float* __restrict__ x,
    const float* __restrict__ qkv_b,
    const float* __restrict__ proj_b,
    const short* __restrict__ wfrag,
    const float* __restrict__ bias2,
    float* __restrict__ out) {
  extern __shared__ short smem[];
  short* buf = smem;              // 2 x [64][200]  x(bf16), then reused for att out
  short* q_l = smem + 25600;      // [6*64][36]  (pre-scaled by SCALE*log2e)
  short* k_l = smem + 39424;      // [6*64][36]
  short* v_l = smem + 53248;      // [192][72]   (v transposed: [d][t])
  short* p_s = smem + 67072;      // 12 x [16][72]  per-wave P scratch

  const short* wq = wfrag;
  const short* wp = wfrag + QKV_FRAG_SH;

  const int tid = threadIdx.x;
  const int w = tid >> 6, lane = tid & 63, quad = lane >> 4, lm = lane & 15;
  const int m = w & 3, g = w >> 2;   // g in 0..2

  // staging index precompute (4 float4 per thread, window = 8 chunks of 1536 floats)
  int goff[4], loff[4];
  #pragma unroll
  for (int i = 0; i < 4; ++i) {
    int idx4 = tid + i * 768;
    int chunk = idx4 / 384;
    int off = idx4 - chunk * 384;
    goff[i] = chunk * 49152 + off * 4;
    loff[i] = (chunk * 8 + off / 48) * 200 + (off % 48) * 4;
  }

  // prologue: stage window it=0
  size_t base;
  {
    int wid = blockIdx.x;
    int b = wid >> 10, rem = wid & 1023, wh = rem >> 5, ww = rem & 31;
    base = ((size_t)b * 65536 + (size_t)(wh * 8) * 256 + (size_t)(ww * 8)) * 192;
    const float* xp = x + base;
    #pragma unroll
    for (int i = 0; i < 4; ++i) {
      float4 f = *(const float4*)(xp + goff[i]);
      short4 s = { f2bf(f.x), f2bf(f.y), f2bf(f.z), f2bf(f.w) };
      *(short4*)&buf[loff[i]] = s;
    }
  }
  __syncthreads();

  float4 pf[4];
  size_t nbase = 0;
  #pragma unroll 1
  for (int it = 0; it < 16; ++it) {
    const int cur = (it & 1) * 12800;
    const int nxt = 12800 - cur;

    // prefetch next window into regs (lands during QKV phase)
    if (it < 15) {
      int wid = (it + 1) * 256 + blockIdx.x;
      int b = wid >> 10, rem = wid & 1023, wh = rem >> 5, ww = rem & 31;
      nbase = ((size_t)b * 65536 + (size_t)(wh * 8) * 256 + (size_t)(ww * 8)) * 192;
      const float* xp = x + nbase;
      #pragma unroll
      for (int i = 0; i < 4; ++i) pf[i] = *(const float4*)(xp + goff[i]);
    }

    // ---------------- QKV: M=64, N=576, K=192 ----------------
    // wave w: m-tile = w&3, n-tiles g*12 .. +12 (4 waves share each n-stream -> L1 reuse)
    {
      bf16x8 af[6];
      #pragma unroll
      for (int ks = 0; ks < 6; ++ks)
        af[ks] = *(const bf16x8*)&buf[cur + (m * 16 + lm) * 200 + ks * 32 + quad * 8];
      const int nt0 = g * 12;
      for (int ntl = 0; ntl < 12; ++ntl) {
        int nt = nt0 + ntl;
        f32x4 acc = {0.f, 0.f, 0.f, 0.f};
        #pragma unroll
        for (int ks = 0; ks < 6; ++ks) {
          bf16x8 bw = *(const bf16x8*)&wq[((nt * 6 + ks) * 64 + lane) * 8];
          acc = __builtin_amdgcn_mfma_f32_16x16x32_bf16(af[ks], bw, acc, 0, 0, 0);
        }
        float bn = qkv_b[nt * 16 + lm];
        if (nt < 12) {            // q (weights+bias pre-scaled by SCALE*log2e)
          bn *= QSCALE;
          int h = nt >> 1, dh = nt & 1;
          int rb = h * 64 + m * 16 + quad * 4;
          #pragma unroll
          for (int r = 0; r < 4; ++r)
            q_l[(rb + r) * 36 + dh * 16 + lm] = f2bf(acc[r] + bn);
        } else if (nt < 24) {     // k
          int h = (nt - 12) >> 1, dh = nt & 1;
          int rb = h * 64 + m * 16 + quad * 4;
          #pragma unroll
          for (int r = 0; r < 4; ++r)
            k_l[(rb + r) * 36 + dh * 16 + lm] = f2bf(acc[r] + bn);
        } else {                  // v transposed [d][t], 4 consecutive t -> short4
          int h = (nt - 24) >> 1, dh = nt & 1;
          short4 s4 = { f2bf(acc[0] + bn), f2bf(acc[1] + bn),
                        f2bf(acc[2] + bn), f2bf(acc[3] + bn) };
          *(short4*)&v_l[(h * 32 + dh * 16 + lm) * 72 + m * 16 + quad * 4] = s4;
        }
      }
    }
    __syncthreads();  // B1: q/k/v ready; x[cur] reads done

    // write prefetched x -> buf[nxt] (consumed next iteration; fenced by B2)
    if (it < 15) {
      #pragma unroll
      for (int i = 0; i < 4; ++i) {
        short4 s = { f2bf(pf[i].x), f2bf(pf[i].y), f2bf(pf[i].z), f2bf(pf[i].w) };
        *(short4*)&buf[nxt + loff[i]] = s;
      }
    }

    // ---------------- attention: 24 (h, mt) tasks, exactly 2 per wave ----------------
    // bias folded into QK acc-init (pre-scaled by log2e); P = exp2(lg);
    // no-max softmax, deferred normalization: o = (P_unnorm V) / rowsum
    {
      const int pb = w * 1152;
      #pragma unroll 1
      for (int i = 0; i < 2; ++i) {
        int tk = w + i * 12;
        int h = tk >> 2, mt = tk & 3;
        const float* bp = bias2 + h * 4096 + (mt * 16 + quad * 4) * 64 + lm;
        f32x4 lg[4];
        #pragma unroll
        for (int nt = 0; nt < 4; ++nt) {
          lg[nt][0] = bp[nt * 16];
          lg[nt][1] = bp[nt * 16 + 64];
          lg[nt][2] = bp[nt * 16 + 128];
          lg[nt][3] = bp[nt * 16 + 192];
        }
        bf16x8 aq = *(const bf16x8*)&q_l[(h * 64 + mt * 16 + lm) * 36 + quad * 8];
        #pragma unroll
        for (int nt = 0; nt < 4; ++nt) {
          bf16x8 bk = *(const bf16x8*)&k_l[(h * 64 + nt * 16 + lm) * 36 + quad * 8];
          lg[nt] = __builtin_amdgcn_mfma_f32_16x16x32_bf16(aq, bk, lg[nt], 0, 0, 0);
        }
        float s[4] = {0.f, 0.f, 0.f, 0.f};
        #pragma unroll
        for (int r = 0; r < 4; ++r) {
          #pragma unroll
          for (int nt = 0; nt < 4; ++nt) {
            float e = exp2f(lg[nt][r]);
            s[r] += e;
            p_s[pb + (quad * 4 + r) * 72 + nt * 16 + lm] = f2bf(e);
          }
        }
        #pragma unroll
        for (int r = 0; r < 4; ++r) {   // overlaps with p_s write drain
          s[r] += __shfl_xor(s[r], 1);
          s[r] += __shfl_xor(s[r], 2);
          s[r] += __shfl_xor(s[r], 4);
          s[r] += __shfl_xor(s[r], 8);
        }
        asm volatile("s_waitcnt lgkmcnt(0)" ::: "memory");  // same-wave P RAW
        f32x4 o0 = {0.f,0.f,0.f,0.f}, o1 = {0.f,0.f,0.f,0.f};
        #pragma unroll
        for (int ks = 0; ks < 2; ++ks) {
          bf16x8 ap  = *(const bf16x8*)&p_s[pb + lm * 72 + ks * 32 + quad * 8];
          bf16x8 bv0 = *(const bf16x8*)&v_l[(h * 32 + lm) * 72 + ks * 32 + quad * 8];
          bf16x8 bv1 = *(const bf16x8*)&v_l[(h * 32 + 16 + lm) * 72 + ks * 32 + quad * 8];
          o0 = __builtin_amdgcn_mfma_f32_16x16x32_bf16(ap, bv0, o0, 0, 0, 0);
          o1 = __builtin_amdgcn_mfma_f32_16x16x32_bf16(ap, bv1, o1, 0, 0, 0);
        }
        #pragma unroll
        for (int r = 0; r < 4; ++r) {
          float ir = 1.0f / s[r];
          int rowo = cur + (mt * 16 + quad * 4 + r) * 200 + h * 32;
          buf[rowo + lm]      = f2bf(o0[r] * ir);
          buf[rowo + 16 + lm] = f2bf(o1[r] * ir);
        }
      }
    }
    __syncthreads();  // B2: att ready in buf[cur]; prefetch writes to buf[nxt] done

    // ---------------- proj: M=64, N=192, K=192 ----------------
    {
      bf16x8 af2[6];
      #pragma unroll
      for (int ks = 0; ks < 6; ++ks)
        af2[ks] = *(const bf16x8*)&buf[cur + (m * 16 + lm) * 200 + ks * 32 + quad * 8];
      const int nt0 = g * 4;
      #pragma unroll 1
      for (int ntl = 0; ntl < 4; ++ntl) {
        int nt = nt0 + ntl;
        f32x4 acc = {0.f, 0.f, 0.f, 0.f};
        #pragma unroll
        for (int ks = 0; ks < 6; ++ks) {
          bf16x8 bw = *(const bf16x8*)&wp[((nt * 6 + ks) * 64 + lane) * 8];
          acc = __builtin_amdgcn_mfma_f32_16x16x32_bf16(af2[ks], bw, acc, 0, 0, 0);
        }
        float pbv = proj_b[nt * 16 + lm];
        #pragma unroll
        for (int r = 0; r < 4; ++r) {
          int t = m * 16 + quad * 4 + r;
          out[base + (size_t)((t >> 3) * 256 + (t & 7)) * 192 + nt * 16 + lm] = acc[r] + pbv;
        }
      }
    }
    base = nbase;
  }
}

extern "C" void kernel_launch(void* const* d_in, const int* in_sizes, int n_in,
                              void* d_out, int out_size, void* d_ws, size_t ws_size,
                              hipStream_t stream) {
  const float* x      = (const float*)d_in[0];
  const float* qkv_w  = (const float*)d_in[1];
  const float* qkv_b  = (const float*)d_in[2];
  const float* proj_w = (const float*)d_in[3];
  const float* proj_b = (const float*)d_in[4];
  const float* bias   = (const float*)d_in[5];
  short* wfrag = (short*)d_ws;                           // 294912 B
  float* bias2 = (float*)((char*)d_ws + BIAS2_OFF_B);    // 98304 B

  hipFuncSetAttribute((const void*)swin_fused,
                      hipFuncAttributeMaxDynamicSharedMemorySize, SMEM_BYTES);

  hipLaunchKernelGGL(cvt_w, dim3(672), dim3(256), 0, stream,
                     qkv_w, proj_w, bias, wfrag, bias2);
  hipLaunchKernelGGL(swin_fused, dim3(256), dim3(768), SMEM_BYTES, stream,
                     x, qkv_b, proj_b, wfrag, bias2, (float*)d_out);
}

// Round 2
// 543.248 us; speedup vs baseline: 1.1107x; 1.0549x over previous
//
#include <hip/hip_runtime.h>

typedef short bf16x8 __attribute__((ext_vector_type(8)));
typedef float f32x4 __attribute__((ext_vector_type(4)));

#define QKV_FRAG_SH 110592
#define PROJ_FRAG_SH 36864
#define BIAS2_OFF_B 294912
#define QKVB2_OFF_B 393216
#define SCALE 0.17677669529663689f
#define LOG2E 1.44269504088896341f
#define QSCALE (SCALE * LOG2E)
#define SMEM_BYTES 161792

__device__ __forceinline__ short f2bf(float f) {
  unsigned x = __float_as_uint(f);
  x = (x + 0x7FFFu + ((x >> 16) & 1u)) >> 16;
  return (short)x;
}

// Pre-transform:
//  - weights -> MFMA-fragment-contiguous bf16 (1 wave frag load = 1KB contiguous)
//  - q weights pre-scaled by SCALE*log2e (exp2 softmax)
//  - bias -> bias*log2e, re-laid so each lane loads its 16 values as 4 float4
//  - qkv_b -> prescaled copy (q part * QSCALE) for accumulator-init folding
__global__ void cvt_w(const float* __restrict__ qkv_w,
                      const float* __restrict__ proj_w,
                      const float* __restrict__ bias,
                      const float* __restrict__ qkv_b,
                      short* __restrict__ wfrag,
                      float* __restrict__ bias2,
                      float* __restrict__ qkvb2) {
  int idx = blockIdx.x * 256 + threadIdx.x;
  if (idx < QKV_FRAG_SH) {
    int j = idx & 7, lane = (idx >> 3) & 63, t = idx >> 9;
    int nt = t / 6, ks = t - nt * 6;
    int n0 = nt * 16 + (lane & 15);
    float v = qkv_w[n0 * 192 + ks * 32 + (lane >> 4) * 8 + j];
    if (n0 < 192) v *= QSCALE;
    wfrag[idx] = f2bf(v);
  } else if (idx < QKV_FRAG_SH + PROJ_FRAG_SH) {
    int i2 = idx - QKV_FRAG_SH;
    int j = i2 & 7, lane = (i2 >> 3) & 63, t = i2 >> 9;
    int nt = t / 6, ks = t - nt * 6;
    wfrag[idx] = f2bf(proj_w[(nt * 16 + (lane & 15)) * 192 + ks * 32 + (lane >> 4) * 8 + j]);
  } else if (idx < QKV_FRAG_SH + PROJ_FRAG_SH + 24576) {
    // bias2[((h*4+mt)*64 + lane)*16 + nt*4 + r] = bias[h][mt*16+(lane>>4)*4+r][nt*16+(lane&15)] * LOG2E
    int i3 = idx - (QKV_FRAG_SH + PROJ_FRAG_SH);
    int r = i3 & 3, nt = (i3 >> 2) & 3, lane = (i3 >> 4) & 63, mt = (i3 >> 10) & 3, h = i3 >> 12;
    int row = mt * 16 + (lane >> 4) * 4 + r;
    int col = nt * 16 + (lane & 15);
    bias2[i3] = bias[h * 4096 + row * 64 + col] * LOG2E;
  } else if (idx < QKV_FRAG_SH + PROJ_FRAG_SH + 24576 + 576) {
    int i4 = idx - (QKV_FRAG_SH + PROJ_FRAG_SH + 24576);
    qkvb2[i4] = qkv_b[i4] * (i4 < 192 ? QSCALE : 1.0f);
  }
}

// Persistent: grid=256 blocks (1/CU), 768 threads (12 waves, 3/SIMD), 16 windows each.
// Per window: [prefetch next x] QKV | B1 | [write prefetch] attention (2 tasks/wave) | B2 | proj.
// GEMM decomposition: each wave owns n-tiles x ALL 4 m-tiles so every weight
// fragment load (1KB via L1) feeds 4 MFMAs (4x less L1 weight traffic than m-split).
__global__ __launch_bounds__(768, 3) void swin_fused(
    const float* __restrict__ x,
    const float* __restrict__ proj_b,
    const short* __restrict__ wfrag,
    const float* __restrict__ bias2,
    const float* __restrict__ qkvb2,
    float* __restrict__ out) {
  extern __shared__ short smem[];
  short* buf = smem;              // 2 x [64][200]  x(bf16), then reused for att out
  short* q_l = smem + 25600;      // [6*64][36]  (pre-scaled by SCALE*log2e)
  short* k_l = smem + 39424;      // [6*64][36]
  short* v_l = smem + 53248;      // [192][72]   (v transposed: [d][t])
  short* p_s = smem + 67072;      // 12 x [16][72]  per-wave P scratch

  const short* wq = wfrag;
  const short* wp = wfrag + QKV_FRAG_SH;

  const int tid = threadIdx.x;
  const int w = tid >> 6, lane = tid & 63, quad = lane >> 4, lm = lane & 15;

  // staging index precompute (4 float4 per thread, window = 8 chunks of 1536 floats)
  int goff[4], loff[4];
  #pragma unroll
  for (int i = 0; i < 4; ++i) {
    int idx4 = tid + i * 768;
    int chunk = idx4 / 384;
    int off = idx4 - chunk * 384;
    goff[i] = chunk * 49152 + off * 4;
    loff[i] = (chunk * 8 + off / 48) * 200 + (off % 48) * 4;
  }

  // prologue: stage window it=0
  size_t base;
  {
    int wid = blockIdx.x;
    int b = wid >> 10, rem = wid & 1023, wh = rem >> 5, ww = rem & 31;
    base = ((size_t)b * 65536 + (size_t)(wh * 8) * 256 + (size_t)(ww * 8)) * 192;
    const float* xp = x + base;
    #pragma unroll
    for (int i = 0; i < 4; ++i) {
      float4 f = *(const float4*)(xp + goff[i]);
      short4 s = { f2bf(f.x), f2bf(f.y), f2bf(f.z), f2bf(f.w) };
      *(short4*)&buf[loff[i]] = s;
    }
  }
  __syncthreads();

  float4 pf[4];
  size_t nbase = 0;
  #pragma unroll 1
  for (int it = 0; it < 16; ++it) {
    const int cur = (it & 1) * 12800;
    const int nxt = 12800 - cur;

    // prefetch next window into regs (lands during QKV phase)
    if (it < 15) {
      int wid = (it + 1) * 256 + blockIdx.x;
      int b = wid >> 10, rem = wid & 1023, wh = rem >> 5, ww = rem & 31;
      nbase = ((size_t)b * 65536 + (size_t)(wh * 8) * 256 + (size_t)(ww * 8)) * 192;
      const float* xp = x + nbase;
      #pragma unroll
      for (int i = 0; i < 4; ++i) pf[i] = *(const float4*)(xp + goff[i]);
    }

    // ---------------- QKV: M=64, N=576, K=192 ----------------
    // wave w: n-tiles w*3..w*3+2 (one q/k/v class per wave), all 4 m-tiles.
    // bias pre-folded into accumulator init (depends only on col=lm).
    {
      const int nt0 = w * 3;
      f32x4 acc[3][4];
      #pragma unroll
      for (int j = 0; j < 3; ++j) {
        float bn = qkvb2[(nt0 + j) * 16 + lm];
        #pragma unroll
        for (int mm = 0; mm < 4; ++mm) acc[j][mm] = (f32x4){bn, bn, bn, bn};
      }
      #pragma unroll 2
      for (int ks = 0; ks < 6; ++ks) {
        bf16x8 a[4];
        #pragma unroll
        for (int mm = 0; mm < 4; ++mm)
          a[mm] = *(const bf16x8*)&buf[cur + (mm * 16 + lm) * 200 + ks * 32 + quad * 8];
        #pragma unroll
        for (int j = 0; j < 3; ++j) {
          bf16x8 bwf = *(const bf16x8*)&wq[((nt0 + j) * 6 + ks) * 512 + lane * 8];
          #pragma unroll
          for (int mm = 0; mm < 4; ++mm)
            acc[j][mm] = __builtin_amdgcn_mfma_f32_16x16x32_bf16(a[mm], bwf, acc[j][mm], 0, 0, 0);
        }
      }
      if (w < 4) {                // q: nt in [0,12)
        #pragma unroll
        for (int j = 0; j < 3; ++j) {
          int nt = nt0 + j, h = nt >> 1, dh = nt & 1;
          #pragma unroll
          for (int mm = 0; mm < 4; ++mm) {
            int rb = h * 64 + mm * 16 + quad * 4;
            #pragma unroll
            for (int r = 0; r < 4; ++r)
              q_l[(rb + r) * 36 + dh * 16 + lm] = f2bf(acc[j][mm][r]);
          }
        }
      } else if (w < 8) {         // k: nt in [12,24)
        #pragma unroll
        for (int j = 0; j < 3; ++j) {
          int nt = nt0 + j, h = (nt - 12) >> 1, dh = nt & 1;
          #pragma unroll
          for (int mm = 0; mm < 4; ++mm) {
            int rb = h * 64 + mm * 16 + quad * 4;
            #pragma unroll
            for (int r = 0; r < 4; ++r)
              k_l[(rb + r) * 36 + dh * 16 + lm] = f2bf(acc[j][mm][r]);
          }
        }
      } else {                    // v: nt in [24,36), transposed [d][t]
        #pragma unroll
        for (int j = 0; j < 3; ++j) {
          int nt = nt0 + j, h = (nt - 24) >> 1, dh = nt & 1;
          #pragma unroll
          for (int mm = 0; mm < 4; ++mm) {
            short4 s4 = { f2bf(acc[j][mm][0]), f2bf(acc[j][mm][1]),
                          f2bf(acc[j][mm][2]), f2bf(acc[j][mm][3]) };
            *(short4*)&v_l[(h * 32 + dh * 16 + lm) * 72 + mm * 16 + quad * 4] = s4;
          }
        }
      }
    }
    __syncthreads();  // B1: q/k/v ready; x[cur] reads done

    // write prefetched x -> buf[nxt] (consumed next iteration; fenced by B2)
    if (it < 15) {
      #pragma unroll
      for (int i = 0; i < 4; ++i) {
        short4 s = { f2bf(pf[i].x), f2bf(pf[i].y), f2bf(pf[i].z), f2bf(pf[i].w) };
        *(short4*)&buf[nxt + loff[i]] = s;
      }
    }

    // ---------------- attention: 24 (h, mt) tasks, exactly 2 per wave ----------------
    // bias folded into QK acc-init (pre-scaled by log2e); P = exp2(lg);
    // no-max softmax, deferred normalization: o = (P_unnorm V) / rowsum
    {
      const int pb = w * 1152;
      #pragma unroll 1
      for (int i = 0; i < 2; ++i) {
        int tk = w + i * 12;
        int h = tk >> 2, mt = tk & 3;
        const float* bp = bias2 + ((h * 4 + mt) * 64 + lane) * 16;
        f32x4 lg[4];
        #pragma unroll
        for (int nt = 0; nt < 4; ++nt)
          lg[nt] = *(const f32x4*)(bp + nt * 4);
        bf16x8 aq = *(const bf16x8*)&q_l[(h * 64 + mt * 16 + lm) * 36 + quad * 8];
        #pragma unroll
        for (int nt = 0; nt < 4; ++nt) {
          bf16x8 bk = *(const bf16x8*)&k_l[(h * 64 + nt * 16 + lm) * 36 + quad * 8];
          lg[nt] = __builtin_amdgcn_mfma_f32_16x16x32_bf16(aq, bk, lg[nt], 0, 0, 0);
        }
        float s[4] = {0.f, 0.f, 0.f, 0.f};
        #pragma unroll
        for (int r = 0; r < 4; ++r) {
          #pragma unroll
          for (int nt = 0; nt < 4; ++nt) {
            float e = exp2f(lg[nt][r]);
            s[r] += e;
            p_s[pb + (quad * 4 + r) * 72 + nt * 16 + lm] = f2bf(e);
          }
        }
        #pragma unroll
        for (int r = 0; r < 4; ++r) {   // overlaps with p_s write drain
          s[r] += __shfl_xor(s[r], 1);
          s[r] += __shfl_xor(s[r], 2);
          s[r] += __shfl_xor(s[r], 4);
          s[r] += __shfl_xor(s[r], 8);
        }
        asm volatile("s_waitcnt lgkmcnt(0)" ::: "memory");  // same-wave P RAW
        f32x4 o0 = {0.f,0.f,0.f,0.f}, o1 = {0.f,0.f,0.f,0.f};
        #pragma unroll
        for (int ks = 0; ks < 2; ++ks) {
          bf16x8 ap  = *(const bf16x8*)&p_s[pb + lm * 72 + ks * 32 + quad * 8];
          bf16x8 bv0 = *(const bf16x8*)&v_l[(h * 32 + lm) * 72 + ks * 32 + quad * 8];
          bf16x8 bv1 = *(const bf16x8*)&v_l[(h * 32 + 16 + lm) * 72 + ks * 32 + quad * 8];
          o0 = __builtin_amdgcn_mfma_f32_16x16x32_bf16(ap, bv0, o0, 0, 0, 0);
          o1 = __builtin_amdgcn_mfma_f32_16x16x32_bf16(ap, bv1, o1, 0, 0, 0);
        }
        #pragma unroll
        for (int r = 0; r < 4; ++r) {
          float ir = 1.0f / s[r];
          int rowo = cur + (mt * 16 + quad * 4 + r) * 200 + h * 32;
          buf[rowo + lm]      = f2bf(o0[r] * ir);
          buf[rowo + 16 + lm] = f2bf(o1[r] * ir);
        }
      }
    }
    __syncthreads();  // B2: att ready in buf[cur]; prefetch writes to buf[nxt] done

    // ---------------- proj: M=64, N=192, K=192 ----------------
    // wave w: n-tile w, all 4 m-tiles; bias folded into acc init.
    {
      const int nt = w;
      float pbv = proj_b[nt * 16 + lm];
      f32x4 acc[4];
      #pragma unroll
      for (int mm = 0; mm < 4; ++mm) acc[mm] = (f32x4){pbv, pbv, pbv, pbv};
      #pragma unroll 2
      for (int ks = 0; ks < 6; ++ks) {
        bf16x8 bwf = *(const bf16x8*)&wp[(nt * 6 + ks) * 512 + lane * 8];
        #pragma unroll
        for (int mm = 0; mm < 4; ++mm) {
          bf16x8 am = *(const bf16x8*)&buf[cur + (mm * 16 + lm) * 200 + ks * 32 + quad * 8];
          acc[mm] = __builtin_amdgcn_mfma_f32_16x16x32_bf16(am, bwf, acc[mm], 0, 0, 0);
        }
      }
      #pragma unroll
      for (int mm = 0; mm < 4; ++mm) {
        #pragma unroll
        for (int r = 0; r < 4; ++r) {
          int t = mm * 16 + quad * 4 + r;
          out[base + (size_t)((t >> 3) * 256 + (t & 7)) * 192 + nt * 16 + lm] = acc[mm][r];
        }
      }
    }
    base = nbase;
  }
}

extern "C" void kernel_launch(void* const* d_in, const int* in_sizes, int n_in,
                              void* d_out, int out_size, void* d_ws, size_t ws_size,
                              hipStream_t stream) {
  const float* x      = (const float*)d_in[0];
  const float* qkv_w  = (const float*)d_in[1];
  const float* qkv_b  = (const float*)d_in[2];
  const float* proj_w = (const float*)d_in[3];
  const float* proj_b = (const float*)d_in[4];
  const float* bias   = (const float*)d_in[5];
  short* wfrag = (short*)d_ws;                           // 294912 B
  float* bias2 = (float*)((char*)d_ws + BIAS2_OFF_B);    // 98304 B
  float* qkvb2 = (float*)((char*)d_ws + QKVB2_OFF_B);    // 2304 B

  hipFuncSetAttribute((const void*)swin_fused,
                      hipFuncAttributeMaxDynamicSharedMemorySize, SMEM_BYTES);

  hipLaunchKernelGGL(cvt_w, dim3(675), dim3(256), 0, stream,
                     qkv_w, proj_w, bias, qkv_b, wfrag, bias2, qkvb2);
  hipLaunchKernelGGL(swin_fused, dim3(256), dim3(768), SMEM_BYTES, stream,
                     x, proj_b, wfrag, bias2, qkvb2, (float*)d_out);
}